// Round 9
// baseline (311.098 us; speedup 1.0000x reference)
//
#include <hip/hip_runtime.h>
#include <stdint.h>
#include <stddef.h>

#define D_DIM 1024
#define T_LEN 4096
#define B_SZ 8
#define M_ROWS 32768   // B_SZ * T_LEN
#define KTOT 1024
#define CHUNK 64
#define NCHUNK 64      // T_LEN / CHUNK

typedef unsigned short u16;
typedef unsigned short u16x8 __attribute__((ext_vector_type(8)));
typedef __bf16 bf16x8 __attribute__((ext_vector_type(8)));
typedef float f32x16 __attribute__((ext_vector_type(16)));

__device__ __forceinline__ u16 f2bf(float f) {
    union { float f; unsigned u; } v; v.f = f;
    unsigned r = v.u + 0x7fffu + ((v.u >> 16) & 1u);
    return (u16)(r >> 16);
}
__device__ __forceinline__ float bf2f(u16 h) {
    union { unsigned u; float f; } v; v.u = ((unsigned)h) << 16;
    return v.f;
}

// ---------------- f32 -> bf16 conversion (vectorized) ----------------
__global__ void convert_kernel(const float* __restrict__ src, u16* __restrict__ dst, int n4) {
    int i = blockIdx.x * blockDim.x + threadIdx.x;
    int stride = gridDim.x * blockDim.x;
    for (int j = i; j < n4; j += stride) {
        float4 v = ((const float4*)src)[j];
        ushort4 o;
        o.x = f2bf(v.x); o.y = f2bf(v.y); o.z = f2bf(v.z); o.w = f2bf(v.w);
        ((ushort4*)dst)[j] = o;
    }
}

// Build wcat (Wk/Wv interleaved at 32-row granularity: rows [64g..64g+31]=Wk[32g..],
// rows [64g+32..64g+63]=Wv[32g..]) and wqb (plain bf16 Wq) in one launch.
__global__ void convert_w_kernel(const float* __restrict__ Wk, const float* __restrict__ Wv,
                                 const float* __restrict__ Wq,
                                 u16* __restrict__ wcat, u16* __restrict__ wqb) {
    int total = 3072 * 256;   // 3072 rows x 256 float4
    int stride = gridDim.x * blockDim.x;
    for (int idx = blockIdx.x * blockDim.x + threadIdx.x; idx < total; idx += stride) {
        int r = idx >> 8, c4 = idx & 255;
        const float* src; u16* dst;
        if (r < 2048) {
            int g = r >> 6, j = r & 63;
            src = (j < 32 ? Wk : Wv) + (size_t)(g * 32 + (j & 31)) * D_DIM;
            dst = wcat + (size_t)r * D_DIM;
        } else {
            src = Wq + (size_t)(r - 2048) * D_DIM;
            dst = wqb + (size_t)(r - 2048) * D_DIM;
        }
        float4 v = ((const float4*)src)[c4];
        ushort4 o;
        o.x = f2bf(v.x); o.y = f2bf(v.y); o.z = f2bf(v.z); o.w = f2bf(v.w);
        ((ushort4*)dst)[c4] = o;
    }
}

// ---------------- async global->LDS, 16B per lane ----------------
__device__ __forceinline__ void gload16(const u16* g, u16* l) {
    __builtin_amdgcn_global_load_lds(
        (const __attribute__((address_space(1))) void*)g,
        (__attribute__((address_space(3))) void*)l,
        16, 0, 0);
}

// phase-top wait: drain previous phase's ds_reads, then fence so MFMA can't
// hoist above (rule #18); body below is left unfenced.
#define LGKM0_FENCE() do { \
    asm volatile("s_waitcnt lgkmcnt(0)" ::: "memory"); \
    __builtin_amdgcn_sched_barrier(0); } while (0)

// ---------------- 32x32x16 pipelined GEMM: C[r,c] = sum_k A[r,k]*B[c,k] ----
// BM=BN=256, BK=64, 8 waves (2Mx4N), per-wave 128x64 = 4x2 tiles of 32x32.
// LDS 2x64KB dbuf. 4 phases/K-tile (one 16-K slice each): phase =
// {[vmcnt/BAR] lgkm0-fence | reads(next slice, 6x b128) + stage + 8 MFMA}.
// Fragment layout 32x32x16: lane holds row=l&31, k=8*(l>>5)..+8 (A and B);
// C/D: col=lane&31, row=(reg&3)+8*(reg>>2)+4*(lane>>5)  [m74/m101].
template<bool CAT>
__global__ __launch_bounds__(512, 2) void gemm8_kernel(
    const u16* __restrict__ A,
    const u16* __restrict__ Bg,
    const float* __restrict__ bias0,
    const float* __restrict__ bias1,
    u16* __restrict__ Uout,
    float* __restrict__ Fout)
{
    constexpr int NT = KTOT / 64;      // 16 K-tiles
    __shared__ u16 smem[2 * 32768];    // 128 KB: buf*32768 + {A:0 | B:16384} + half*8192

    const int tid  = threadIdx.x;
    const int w    = tid >> 6;
    const int lane = tid & 63;

    // XCD-aware swizzle (grid % 8 == 0)
    const int cpx = gridDim.x >> 3;
    const int swz = (blockIdx.x & 7) * cpx + (blockIdx.x >> 3);
    const int nCol = CAT ? 8 : 4;
    const int M0 = (swz / nCol) * 256;
    const int N0 = (swz % nCol) * 256;

    // staging: gload16 covers 16 rows x 32 cols; lane -> row=lane>>2, slot=lane&3;
    // global src pre-swizzled so stored granule s holds k-granule s ^ ((row>>1)&3).
    const int srow = lane >> 2;
    const int sg   = (lane & 3) ^ ((srow >> 1) & 3);

    const u16* pA0 = A  + (size_t)(M0 + w * 32 +      srow) * KTOT + sg * 8;
    const u16* pA1 = A  + (size_t)(M0 + w * 32 + 16 + srow) * KTOT + sg * 8;
    const u16* pB0 = Bg + (size_t)(N0 + w * 32 +      srow) * KTOT + sg * 8;
    const u16* pB1 = Bg + (size_t)(N0 + w * 32 + 16 + srow) * KTOT + sg * 8;

    auto stA = [&](u16* nxt, int h) {
        gload16(pA0, nxt + h * 8192 + w * 1024);       pA0 += 32;
        gload16(pA1, nxt + h * 8192 + w * 1024 + 512); pA1 += 32;
    };
    auto stB = [&](u16* nxt, int h) {
        gload16(pB0, nxt + 16384 + h * 8192 + w * 1024);       pB0 += 32;
        gload16(pB1, nxt + 16384 + h * 8192 + w * 1024 + 512); pB1 += 32;
    };

    const int wrow = (w >> 2) * 128;   // M offset of wave tile (128 rows)
    const int wcol = (w & 3) * 64;     // N offset of wave tile (64 cols)
    const int l31 = lane & 31;
    const int hi  = lane >> 5;

    // LDS element (row r, k): u16addr = (k>>5)*8192 + r*32 + (((k&31)>>3 ^ ((r>>1)&3))<<3) + (k&7)
    // 32x32x16 frag (slice ks, 16 k): lane reads 8 u16 at granule ((ks&1)*2 | hi)
    int offA[4][4], offB[2][4];
#pragma unroll
    for (int m = 0; m < 4; ++m) {
        int row = wrow + m * 32 + l31;
        int rm = (row >> 1) & 3;
#pragma unroll
        for (int ks = 0; ks < 4; ++ks)
            offA[m][ks] = (ks >> 1) * 8192 + row * 32 + ((((ks & 1) * 2 + hi) ^ rm) << 3);
    }
#pragma unroll
    for (int n = 0; n < 2; ++n) {
        int row = wcol + n * 32 + l31;
        int rm = (row >> 1) & 3;
#pragma unroll
        for (int ks = 0; ks < 4; ++ks)
            offB[n][ks] = 16384 + (ks >> 1) * 8192 + row * 32 + ((((ks & 1) * 2 + hi) ^ rm) << 3);
    }

    f32x16 acc[4][2] = {};
    bf16x8 aP[4], bP[2], aQ[4], bQ[2];

    // prologue: stage tile 0, confirm ks0/ks1 half, read slice-0 fragments
    stA(smem, 0); stB(smem, 0); stA(smem, 1); stB(smem, 1);
    asm volatile("s_waitcnt vmcnt(4)" ::: "memory");
    __builtin_amdgcn_s_barrier();
#pragma unroll
    for (int m = 0; m < 4; ++m) aP[m] = *(const bf16x8*)(smem + offA[m][0]);
#pragma unroll
    for (int n = 0; n < 2; ++n) bP[n] = *(const bf16x8*)(smem + offB[n][0]);

#pragma unroll 1
    for (int t = 0; t < NT; ++t) {
        const u16* cur = smem + (t & 1) * 32768;
        u16* nxt = smem + ((t + 1) & 1) * 32768;
        const bool pf = (t + 1 < NT);

        // ===== p0: wait P(ks0); body: read Q<-ks1 + stage A-h0(t+1) + MFMA ks0 =====
        LGKM0_FENCE();
#pragma unroll
        for (int m = 0; m < 4; ++m) aQ[m] = *(const bf16x8*)(cur + offA[m][1]);
#pragma unroll
        for (int n = 0; n < 2; ++n) bQ[n] = *(const bf16x8*)(cur + offB[n][1]);
        if (pf) stA(nxt, 0);
#pragma unroll
        for (int m = 0; m < 4; ++m)
#pragma unroll
            for (int n = 0; n < 2; ++n)
                acc[m][n] = __builtin_amdgcn_mfma_f32_32x32x16_bf16(aP[m], bP[n], acc[m][n], 0, 0, 0);

        // ===== p1: vmcnt covers tile-t h1; BAR; wait Q(ks1);
        //           body: read P<-ks2 + stage B-h0(t+1) + MFMA ks1 =====
        if (pf) { asm volatile("s_waitcnt vmcnt(2)" ::: "memory"); }
        else    { asm volatile("s_waitcnt vmcnt(0)" ::: "memory"); }
        __builtin_amdgcn_s_barrier();
        LGKM0_FENCE();
#pragma unroll
        for (int m = 0; m < 4; ++m) aP[m] = *(const bf16x8*)(cur + offA[m][2]);
#pragma unroll
        for (int n = 0; n < 2; ++n) bP[n] = *(const bf16x8*)(cur + offB[n][2]);
        if (pf) stB(nxt, 0);
#pragma unroll
        for (int m = 0; m < 4; ++m)
#pragma unroll
            for (int n = 0; n < 2; ++n)
                acc[m][n] = __builtin_amdgcn_mfma_f32_32x32x16_bf16(aQ[m], bQ[n], acc[m][n], 0, 0, 0);

        // ===== p2: wait P(ks2); body: read Q<-ks3 + stage A-h1(t+1) + MFMA ks2 =====
        LGKM0_FENCE();
#pragma unroll
        for (int m = 0; m < 4; ++m) aQ[m] = *(const bf16x8*)(cur + offA[m][3]);
#pragma unroll
        for (int n = 0; n < 2; ++n) bQ[n] = *(const bf16x8*)(cur + offB[n][3]);
        if (pf) stA(nxt, 1);
#pragma unroll
        for (int m = 0; m < 4; ++m)
#pragma unroll
            for (int n = 0; n < 2; ++n)
                acc[m][n] = __builtin_amdgcn_mfma_f32_32x32x16_bf16(aP[m], bP[n], acc[m][n], 0, 0, 0);

        // ===== p3: vmcnt covers tile-(t+1) h0; BAR; wait Q(ks3);
        //           body: read P<-ks0(next) + stage B-h1(t+1) + MFMA ks3 =====
        if (pf) { asm volatile("s_waitcnt vmcnt(2)" ::: "memory"); }
        __builtin_amdgcn_s_barrier();
        LGKM0_FENCE();
        if (pf) {
#pragma unroll
            for (int m = 0; m < 4; ++m) aP[m] = *(const bf16x8*)(nxt + offA[m][0]);
#pragma unroll
            for (int n = 0; n < 2; ++n) bP[n] = *(const bf16x8*)(nxt + offB[n][0]);
            stB(nxt, 1);
        }
#pragma unroll
        for (int m = 0; m < 4; ++m)
#pragma unroll
            for (int n = 0; n < 2; ++n)
                acc[m][n] = __builtin_amdgcn_mfma_f32_32x32x16_bf16(aQ[m], bQ[n], acc[m][n], 0, 0, 0);
    }

    asm volatile("s_waitcnt lgkmcnt(0) vmcnt(0)" ::: "memory");

    // epilogue: C/D layout col=lane&31, row=(reg&3)+8*(reg>>2)+4*(lane>>5)
    if (CAT) {
        // wave's 64 wcat cols = pair-group G: cols n=0 -> Wk rows 32G.., n=1 -> Wv
        const int Gu = (N0 >> 6) + (w & 3);
        const int ucol = Gu * 32 + l31;
        const float b0 = bias0[ucol];
        const float b1 = bias1[ucol];
#pragma unroll
        for (int m = 0; m < 4; ++m) {
            int row0 = M0 + wrow + m * 32 + 4 * hi;
#pragma unroll
            for (int j = 0; j < 16; ++j) {
                int row = row0 + (j & 3) + 8 * (j >> 2);
                float kl = acc[m][0][j] + b0;
                float vv = acc[m][1][j] + b1;
                float sig = 1.0f / (1.0f + __expf(-kl));
                Uout[(size_t)row * D_DIM + ucol] = f2bf(sig * vv);
            }
        }
    } else {
#pragma unroll
        for (int n = 0; n < 2; ++n) {
            int col = N0 + wcol + n * 32 + l31;
            float b0 = bias0[col];
            float b1 = bias1[col];
#pragma unroll
            for (int m = 0; m < 4; ++m) {
                int row0 = M0 + wrow + m * 32 + 4 * hi;
#pragma unroll
                for (int j = 0; j < 16; ++j) {
                    int row = row0 + (j & 3) + 8 * (j >> 2);
                    Fout[(size_t)row * D_DIM + col] = (acc[m][n][j] + b0) / b1;
                }
            }
        }
    }
}

// ---------------- scan pass A: per-chunk carry (x8 vectorized) ----------------
__global__ void chunk_carry_kernel(const u16* __restrict__ u, const float* __restrict__ decay,
                                   float* __restrict__ localc) {
    int id = blockIdx.x * blockDim.x + threadIdx.x;   // B*NCHUNK*(D/8) = 65536
    int d8 = id & 127;
    int c  = (id >> 7) & (NCHUNK - 1);
    int b  = id >> 13;
    float4 dlo = ((const float4*)decay)[d8 * 2];
    float4 dhi = ((const float4*)decay)[d8 * 2 + 1];
    float dec[8] = {dlo.x, dlo.y, dlo.z, dlo.w, dhi.x, dhi.y, dhi.z, dhi.w};
    float carry[8] = {};
    const u16* up = u + ((size_t)b * T_LEN + (size_t)c * CHUNK) * D_DIM + d8 * 8;
    for (int s = 0; s < CHUNK; ++s) {
        u16x8 v = *(const u16x8*)(up + (size_t)s * D_DIM);
#pragma unroll
        for (int j = 0; j < 8; ++j)
            carry[j] = fmaf(carry[j], dec[j], bf2f(v[j]));
    }
    float* lc = localc + ((size_t)(b * NCHUNK + c)) * D_DIM + d8 * 8;
#pragma unroll
    for (int j = 0; j < 8; ++j) lc[j] = carry[j];
}

// ---------------- scan pass B: exclusive scan over chunk carries ----------------
__global__ void carry_scan_kernel(const float* __restrict__ localc, const float* __restrict__ state_p,
                                  const float* __restrict__ decay, float* __restrict__ prefix,
                                  float* __restrict__ final_p) {
    int id = blockIdx.x * blockDim.x + threadIdx.x;   // B*D = 8192
    int d = id & (D_DIM - 1);
    int b = id >> 10;
    float dec = decay[d];
    float dl = dec;
#pragma unroll
    for (int i = 0; i < 6; ++i) dl *= dl;             // dec^64
    float P = state_p[id];
    for (int c = 0; c < NCHUNK; ++c) {
        int idx = (b * NCHUNK + c) * D_DIM + d;
        prefix[idx] = P;
        P = fmaf(P, dl, localc[idx]);
    }
    final_p[id] = P;
}

// ---------------- scan pass C: reconstruct p in place (x8 vectorized) ----------------
__global__ void reconstruct_kernel(u16* __restrict__ u, const float* __restrict__ decay,
                                   const float* __restrict__ prefix) {
    int id = blockIdx.x * blockDim.x + threadIdx.x;   // 65536
    int d8 = id & 127;
    int c  = (id >> 7) & (NCHUNK - 1);
    int b  = id >> 13;
    float4 dlo = ((const float4*)decay)[d8 * 2];
    float4 dhi = ((const float4*)decay)[d8 * 2 + 1];
    float dec[8] = {dlo.x, dlo.y, dlo.z, dlo.w, dhi.x, dhi.y, dhi.z, dhi.w};
    const float* pf = prefix + ((size_t)(b * NCHUNK + c)) * D_DIM + d8 * 8;
    float p[8];
#pragma unroll
    for (int j = 0; j < 8; ++j) p[j] = pf[j];
    u16* up = u + ((size_t)b * T_LEN + (size_t)c * CHUNK) * D_DIM + d8 * 8;
    for (int s = 0; s < CHUNK; ++s) {
        u16x8 v = *(const u16x8*)(up + (size_t)s * D_DIM);
        u16x8 o;
#pragma unroll
        for (int j = 0; j < 8; ++j) {
            p[j] = fmaf(p[j], dec[j], bf2f(v[j]));
            o[j] = f2bf(p[j]);
        }
        *(u16x8*)(up + (size_t)s * D_DIM) = o;
    }
}

extern "C" void kernel_launch(void* const* d_in, const int* in_sizes, int n_in,
                              void* d_out, int out_size, void* d_ws, size_t ws_size,
                              hipStream_t stream) {
    const float* x       = (const float*)d_in[0];
    const float* state_p = (const float*)d_in[1];
    const float* decay   = (const float*)d_in[2];
    const float* mass    = (const float*)d_in[3];
    const float* Wq      = (const float*)d_in[4];
    const float* bq      = (const float*)d_in[5];
    const float* Wk      = (const float*)d_in[6];
    const float* bk      = (const float*)d_in[7];
    const float* Wv      = (const float*)d_in[8];
    const float* bv      = (const float*)d_in[9];

    float* out     = (float*)d_out;
    float* final_p = out + (size_t)M_ROWS * D_DIM;

    // x_bf16 staged in d_out's first 64MB (dead before final GEMM overwrites it)
    u16* xb = (u16*)d_out;

    // workspace layout (~74MB)
    u16* wcat = (u16*)d_ws;                          // [2048][1024] interleaved Wk/Wv
    u16* wqb  = wcat + 2048 * 1024;
    u16* ub   = wqb + 1024 * 1024;                   // u then p in place, 64MB
    float* localc = (float*)(ub + (size_t)M_ROWS * D_DIM);
    float* prefix = localc + B_SZ * NCHUNK * D_DIM;

    convert_kernel<<<4096, 256, 0, stream>>>(x, xb, (M_ROWS * D_DIM) / 4);
    convert_w_kernel<<<1536, 256, 0, stream>>>(Wk, Wv, Wq, wcat, wqb);

    // u = sigmoid(x Wk^T + bk) * (x Wv^T + bv)  -- one N=2048 GEMM over wcat
    gemm8_kernel<true><<<dim3(1024), dim3(512), 0, stream>>>(
        xb, wcat, bk, bv, ub, nullptr);

    chunk_carry_kernel<<<256, 256, 0, stream>>>(ub, decay, localc);
    carry_scan_kernel<<<32, 256, 0, stream>>>(localc, state_p, decay, prefix, final_p);
    reconstruct_kernel<<<256, 256, 0, stream>>>(ub, decay, prefix);

    // velocities = (p Wq^T + bq) / mass
    gemm8_kernel<false><<<dim3(512), dim3(512), 0, stream>>>(
        ub, wqb, bq, mass, nullptr, out);
}

// Round 10
// 306.011 us; speedup vs baseline: 1.0166x; 1.0166x over previous
//
#include <hip/hip_runtime.h>
#include <stdint.h>
#include <stddef.h>

#define D_DIM 1024
#define T_LEN 4096
#define B_SZ 8
#define M_ROWS 32768   // B_SZ * T_LEN
#define KTOT 1024
#define CHUNK 64
#define NCHUNK 64      // T_LEN / CHUNK

typedef unsigned short u16;
typedef unsigned short u16x8 __attribute__((ext_vector_type(8)));
typedef __bf16 bf16x8 __attribute__((ext_vector_type(8)));
typedef float f32x4 __attribute__((ext_vector_type(4)));

__device__ __forceinline__ u16 f2bf(float f) {
    union { float f; unsigned u; } v; v.f = f;
    unsigned r = v.u + 0x7fffu + ((v.u >> 16) & 1u);
    return (u16)(r >> 16);
}
__device__ __forceinline__ float bf2f(u16 h) {
    union { unsigned u; float f; } v; v.u = ((unsigned)h) << 16;
    return v.f;
}

// ---------------- f32 -> bf16 conversion (vectorized) ----------------
__global__ void convert_kernel(const float* __restrict__ src, u16* __restrict__ dst, int n4) {
    int i = blockIdx.x * blockDim.x + threadIdx.x;
    int stride = gridDim.x * blockDim.x;
    for (int j = i; j < n4; j += stride) {
        float4 v = ((const float4*)src)[j];
        ushort4 o;
        o.x = f2bf(v.x); o.y = f2bf(v.y); o.z = f2bf(v.z); o.w = f2bf(v.w);
        ((ushort4*)dst)[j] = o;
    }
}

// Build wcat (Wk/Wv interleaved at 16-row granularity: rows [32g..32g+15]=Wk[16g..],
// rows [32g+16..32g+31]=Wv[16g..]) and wqb (plain bf16 Wq) in one launch.
__global__ void convert_w_kernel(const float* __restrict__ Wk, const float* __restrict__ Wv,
                                 const float* __restrict__ Wq,
                                 u16* __restrict__ wcat, u16* __restrict__ wqb) {
    int total = 3072 * 256;   // 3072 rows x 256 float4
    int stride = gridDim.x * blockDim.x;
    for (int idx = blockIdx.x * blockDim.x + threadIdx.x; idx < total; idx += stride) {
        int r = idx >> 8, c4 = idx & 255;
        const float* src; u16* dst;
        if (r < 2048) {
            int g = r >> 5, j = r & 31;
            src = (j < 16 ? Wk : Wv) + (size_t)(g * 16 + (j & 15)) * D_DIM;
            dst = wcat + (size_t)r * D_DIM;
        } else {
            src = Wq + (size_t)(r - 2048) * D_DIM;
            dst = wqb + (size_t)(r - 2048) * D_DIM;
        }
        float4 v = ((const float4*)src)[c4];
        ushort4 o;
        o.x = f2bf(v.x); o.y = f2bf(v.y); o.z = f2bf(v.z); o.w = f2bf(v.w);
        ((ushort4*)dst)[c4] = o;
    }
}

// ---------------- async global->LDS, 16B per lane ----------------
__device__ __forceinline__ void gload16(const u16* g, u16* l) {
    __builtin_amdgcn_global_load_lds(
        (const __attribute__((address_space(1))) void*)g,
        (__attribute__((address_space(3))) void*)l,
        16, 0, 0);
}

// ---------------- deep-prefetch pipelined GEMM: C[r,c] = sum_k A[r,k]*B[c,k]
// BM=BN=256, sub-tile BK=32, ring of 4 LDS buffers (4 x 32KB = 128KB).
// 8 waves (2Mx4N), per-wave 128x64 output. Per sub-tile s:
//   { vmcnt(4 | 0 tail)  -> stage(s+1) landed (all newer stages <= 4 loads)
//     s_barrier          -> cross-wave stage visibility; also W->R ledger
//     lgkmcnt(0)+fence   -> frags(s) (read during body s-1) in registers
//     body: stage(s+3) | read frags(s+1) | 32 MFMA (setprio), free-scheduled }
// Prefetch distance: stage issued ~2 full bodies before its vmcnt wait.
template<bool CAT>
__global__ __launch_bounds__(512, 2) void gemm9_kernel(
    const u16* __restrict__ A,
    const u16* __restrict__ Bg,
    const float* __restrict__ bias0,
    const float* __restrict__ bias1,
    u16* __restrict__ Uout,
    float* __restrict__ Fout)
{
    constexpr int NT = KTOT / 32;      // 32 sub-tiles
    __shared__ u16 smem[4 * 16384];    // 128 KB: buf*16384 + {A:0 | B:8192}

    const int tid  = threadIdx.x;
    const int w    = tid >> 6;
    const int lane = tid & 63;

    // XCD-aware swizzle (grid % 8 == 0)
    const int cpx = gridDim.x >> 3;
    const int swz = (blockIdx.x & 7) * cpx + (blockIdx.x >> 3);
    const int nCol = CAT ? 8 : 4;
    const int M0 = (swz / nCol) * 256;
    const int N0 = (swz % nCol) * 256;

    // staging: gload16 covers 16 rows x 32 cols (512 u16); lane -> row=lane>>2,
    // slot=lane&3; global src pre-swizzled: stored granule g holds kgrp g^((row>>1)&3).
    const int srow = lane >> 2;
    const int sg   = (lane & 3) ^ ((srow >> 1) & 3);

    const u16* pA0 = A  + (size_t)(M0 + w * 32 +      srow) * KTOT + sg * 8;
    const u16* pA1 = A  + (size_t)(M0 + w * 32 + 16 + srow) * KTOT + sg * 8;
    const u16* pB0 = Bg + (size_t)(N0 + w * 32 +      srow) * KTOT + sg * 8;
    const u16* pB1 = Bg + (size_t)(N0 + w * 32 + 16 + srow) * KTOT + sg * 8;

    auto stage = [&](int buf) {
        u16* s = smem + buf * 16384;
        gload16(pA0, s + w * 1024);              pA0 += 32;
        gload16(pA1, s + w * 1024 + 512);        pA1 += 32;
        gload16(pB0, s + 8192 + w * 1024);       pB0 += 32;
        gload16(pB1, s + 8192 + w * 1024 + 512); pB1 += 32;
    };

    const int wrow = (w >> 2) * 128;
    const int wcol = (w & 3) * 64;
    const int fr = lane & 15;
    const int fq = lane >> 4;

    int offA[8], offB[4];
#pragma unroll
    for (int m = 0; m < 8; ++m) {
        int row = wrow + m * 16 + fr;
        offA[m] = row * 32 + ((fq ^ ((row >> 1) & 3)) << 3);
    }
#pragma unroll
    for (int n = 0; n < 4; ++n) {
        int row = wcol + n * 16 + fr;
        offB[n] = 8192 + row * 32 + ((fq ^ ((row >> 1) & 3)) << 3);
    }

    f32x4 acc[8][4] = {};
    bf16x8 aP[8], bP[4], aQ[8], bQ[4];

    // prologue: stage sub-tiles 0..2 (12 loads); ensure stage(0) landed; read frags(0)
    stage(0); stage(1); stage(2);
    asm volatile("s_waitcnt vmcnt(8)" ::: "memory");
    __builtin_amdgcn_s_barrier();
#pragma unroll
    for (int m = 0; m < 8; ++m) aP[m] = *(const bf16x8*)(smem + offA[m]);
#pragma unroll
    for (int n = 0; n < 4; ++n) bP[n] = *(const bf16x8*)(smem + offB[n]);

// One sub-tile. AC/BC = current frags (consumed by MFMA); AN/BN_ = next frags (filled).
// vmcnt ledger at top of s: outstanding stages (issue order) = s+1, s+2[, s+3 not yet].
//   need stage(s+1) retired before body reads frags(s+1):
//   newer-than-(s+1) = stage(s+2) if it exists -> vmcnt(4), else vmcnt(0).
#define SUBTILE(S, AC, BC, AN, BN_)                                                  \
  {                                                                                  \
    const int s_ = (S);                                                              \
    if (s_ + 1 < NT) {                                                               \
      if (s_ + 2 < NT) { asm volatile("s_waitcnt vmcnt(4)" ::: "memory"); }          \
      else             { asm volatile("s_waitcnt vmcnt(0)" ::: "memory"); }          \
    }                                                                                \
    __builtin_amdgcn_s_barrier();                                                    \
    asm volatile("s_waitcnt lgkmcnt(0)" ::: "memory");                               \
    __builtin_amdgcn_sched_barrier(0);                                               \
    if (s_ + 3 < NT) stage((s_ + 3) & 3);                                            \
    if (s_ + 1 < NT) {                                                               \
      const u16* nb_ = smem + ((s_ + 1) & 3) * 16384;                                \
      _Pragma("unroll") for (int m = 0; m < 8; ++m)                                  \
        AN[m] = *(const bf16x8*)(nb_ + offA[m]);                                     \
      _Pragma("unroll") for (int n = 0; n < 4; ++n)                                  \
        BN_[n] = *(const bf16x8*)(nb_ + offB[n]);                                    \
    }                                                                                \
    __builtin_amdgcn_s_setprio(1);                                                   \
    _Pragma("unroll") for (int m = 0; m < 8; ++m)                                    \
      _Pragma("unroll") for (int n = 0; n < 4; ++n)                                  \
        acc[m][n] = __builtin_amdgcn_mfma_f32_16x16x32_bf16(AC[m], BC[n], acc[m][n], 0, 0, 0); \
    __builtin_amdgcn_s_setprio(0);                                                   \
  }

#pragma unroll 1
    for (int s = 0; s < NT; s += 2) {
        SUBTILE(s,     aP, bP, aQ, bQ);
        SUBTILE(s + 1, aQ, bQ, aP, bP);
    }
#undef SUBTILE

    asm volatile("s_waitcnt lgkmcnt(0) vmcnt(0)" ::: "memory");

    // epilogue: C/D layout col=lane&15, row=(lane>>4)*4+reg
    if (CAT) {
        const int ucol0 = N0 / 2 + (w & 3) * 32;
#pragma unroll
        for (int p = 0; p < 2; ++p) {
            int col = ucol0 + p * 16 + fr;
            float b0 = bias0[col];
            float b1 = bias1[col];
#pragma unroll
            for (int m = 0; m < 8; ++m) {
                int row0 = M0 + wrow + m * 16 + fq * 4;
#pragma unroll
                for (int j = 0; j < 4; ++j) {
                    float kl = acc[m][2 * p][j] + b0;
                    float vv = acc[m][2 * p + 1][j] + b1;
                    float sig = 1.0f / (1.0f + __expf(-kl));
                    Uout[(size_t)(row0 + j) * D_DIM + col] = f2bf(sig * vv);
                }
            }
        }
    } else {
#pragma unroll
        for (int n = 0; n < 4; ++n) {
            int col = N0 + wcol + n * 16 + fr;
            float b0 = bias0[col];
            float b1 = bias1[col];
#pragma unroll
            for (int m = 0; m < 8; ++m) {
                int row0 = M0 + wrow + m * 16 + fq * 4;
#pragma unroll
                for (int j = 0; j < 4; ++j)
                    Fout[(size_t)(row0 + j) * D_DIM + col] = (acc[m][n][j] + b0) / b1;
            }
        }
    }
}

// ---------------- scan pass A: per-chunk carry (x8 vectorized) ----------------
__global__ void chunk_carry_kernel(const u16* __restrict__ u, const float* __restrict__ decay,
                                   float* __restrict__ localc) {
    int id = blockIdx.x * blockDim.x + threadIdx.x;   // B*NCHUNK*(D/8) = 65536
    int d8 = id & 127;
    int c  = (id >> 7) & (NCHUNK - 1);
    int b  = id >> 13;
    float4 dlo = ((const float4*)decay)[d8 * 2];
    float4 dhi = ((const float4*)decay)[d8 * 2 + 1];
    float dec[8] = {dlo.x, dlo.y, dlo.z, dlo.w, dhi.x, dhi.y, dhi.z, dhi.w};
    float carry[8] = {};
    const u16* up = u + ((size_t)b * T_LEN + (size_t)c * CHUNK) * D_DIM + d8 * 8;
    for (int s = 0; s < CHUNK; ++s) {
        u16x8 v = *(const u16x8*)(up + (size_t)s * D_DIM);
#pragma unroll
        for (int j = 0; j < 8; ++j)
            carry[j] = fmaf(carry[j], dec[j], bf2f(v[j]));
    }
    float* lc = localc + ((size_t)(b * NCHUNK + c)) * D_DIM + d8 * 8;
#pragma unroll
    for (int j = 0; j < 8; ++j) lc[j] = carry[j];
}

// ---------------- scan pass B: exclusive scan over chunk carries ----------------
__global__ void carry_scan_kernel(const float* __restrict__ localc, const float* __restrict__ state_p,
                                  const float* __restrict__ decay, float* __restrict__ prefix,
                                  float* __restrict__ final_p) {
    int id = blockIdx.x * blockDim.x + threadIdx.x;   // B*D = 8192
    int d = id & (D_DIM - 1);
    int b = id >> 10;
    float dec = decay[d];
    float dl = dec;
#pragma unroll
    for (int i = 0; i < 6; ++i) dl *= dl;             // dec^64
    float P = state_p[id];
    for (int c = 0; c < NCHUNK; ++c) {
        int idx = (b * NCHUNK + c) * D_DIM + d;
        prefix[idx] = P;
        P = fmaf(P, dl, localc[idx]);
    }
    final_p[id] = P;
}

// ---------------- scan pass C: reconstruct p in place (x8 vectorized) ----------------
__global__ void reconstruct_kernel(u16* __restrict__ u, const float* __restrict__ decay,
                                   const float* __restrict__ prefix) {
    int id = blockIdx.x * blockDim.x + threadIdx.x;   // 65536
    int d8 = id & 127;
    int c  = (id >> 7) & (NCHUNK - 1);
    int b  = id >> 13;
    float4 dlo = ((const float4*)decay)[d8 * 2];
    float4 dhi = ((const float4*)decay)[d8 * 2 + 1];
    float dec[8] = {dlo.x, dlo.y, dlo.z, dlo.w, dhi.x, dhi.y, dhi.z, dhi.w};
    const float* pf = prefix + ((size_t)(b * NCHUNK + c)) * D_DIM + d8 * 8;
    float p[8];
#pragma unroll
    for (int j = 0; j < 8; ++j) p[j] = pf[j];
    u16* up = u + ((size_t)b * T_LEN + (size_t)c * CHUNK) * D_DIM + d8 * 8;
    for (int s = 0; s < CHUNK; ++s) {
        u16x8 v = *(const u16x8*)(up + (size_t)s * D_DIM);
        u16x8 o;
#pragma unroll
        for (int j = 0; j < 8; ++j) {
            p[j] = fmaf(p[j], dec[j], bf2f(v[j]));
            o[j] = f2bf(p[j]);
        }
        *(u16x8*)(up + (size_t)s * D_DIM) = o;
    }
}

extern "C" void kernel_launch(void* const* d_in, const int* in_sizes, int n_in,
                              void* d_out, int out_size, void* d_ws, size_t ws_size,
                              hipStream_t stream) {
    const float* x       = (const float*)d_in[0];
    const float* state_p = (const float*)d_in[1];
    const float* decay   = (const float*)d_in[2];
    const float* mass    = (const float*)d_in[3];
    const float* Wq      = (const float*)d_in[4];
    const float* bq      = (const float*)d_in[5];
    const float* Wk      = (const float*)d_in[6];
    const float* bk      = (const float*)d_in[7];
    const float* Wv      = (const float*)d_in[8];
    const float* bv      = (const float*)d_in[9];

    float* out     = (float*)d_out;
    float* final_p = out + (size_t)M_ROWS * D_DIM;

    // x_bf16 staged in d_out's first 64MB (dead before final GEMM overwrites it)
    u16* xb = (u16*)d_out;

    // workspace layout (~74MB)
    u16* wcat = (u16*)d_ws;                          // [2048][1024] interleaved Wk/Wv
    u16* wqb  = wcat + 2048 * 1024;
    u16* ub   = wqb + 1024 * 1024;                   // u then p in place, 64MB
    float* localc = (float*)(ub + (size_t)M_ROWS * D_DIM);
    float* prefix = localc + B_SZ * NCHUNK * D_DIM;

    convert_kernel<<<4096, 256, 0, stream>>>(x, xb, (M_ROWS * D_DIM) / 4);
    convert_w_kernel<<<1536, 256, 0, stream>>>(Wk, Wv, Wq, wcat, wqb);

    // u = sigmoid(x Wk^T + bk) * (x Wv^T + bv)  -- one N=2048 GEMM over wcat
    gemm9_kernel<true><<<dim3(1024), dim3(512), 0, stream>>>(
        xb, wcat, bk, bv, ub, nullptr);

    chunk_carry_kernel<<<256, 256, 0, stream>>>(ub, decay, localc);
    carry_scan_kernel<<<32, 256, 0, stream>>>(localc, state_p, decay, prefix, final_p);
    reconstruct_kernel<<<256, 256, 0, stream>>>(ub, decay, prefix);

    // velocities = (p Wq^T + bq) / mass
    gemm9_kernel<false><<<dim3(512), dim3(512), 0, stream>>>(
        ub, wqb, bq, mass, nullptr, out);
}